// Round 17
// baseline (776.324 us; speedup 1.0000x reference)
//
#include <hip/hip_runtime.h>
#include <hip/hip_fp16.h>

// ---------------------------------------------------------------------------
// RecurrentRepresentationAggregator: 64-step LSTM-ish recurrence, B=512.
//   gates_t = [r_{t-1}, h_{t-1}, z_t] @ W_rnn^T + b_rnn      (N=2048, K=1280)
//   c_t = sig(f)*c + sig(i)*tanh(s);  h_t = sig(o)*tanh(c_t)
//   r_t = r_{t-1} + h_t @ W_feat^T + b_feat                   (N=256, K=512)
//
// Fold: gates_t = Gz_t + r_{t-2}·Wr + h_{t-1}·(Wh + Wf^T Wr).
// ALL Gz precomputed up front (zpack + k_gzbig, 128x128 tiles, 4096 blk,
// bid layout [bmh:5][bn:4][xcd:3] -> A+B L2-resident; gz stores NONTEMPORAL
// (as ushort bit pattern -- builtin rejects __half*) so the 131 MB write
// stream doesn't evict operands from L2).
// Prologue fused to 4 launches: k_init{wft,bias2} -> k_whp4 ->
// k_prep{rinit,packh0,pack_bprec(inline whp sum),pack_bpz,pack_bf,zpackall}
// -> k_gzbig.
// Per step ONE launch, grid 256 x 640 (1 block/CU, 10 waves):
//   waves 0-7: gate 64x64 tile, wave = 32x16 out, 6 indep 8-deep MFMA chains;
//     cls-LDS + barrier + coalesced epilogue (gz/c32 prefetched pre-MFMA).
//   waves 8-9: one 16x16 r-tile each (spread uniformly -- R14 lesson).
// h/rd carried in fp16 MFMA fragment layout; frag map (16x16x32):
// value(row,k) at lane=(row&15)+16*((k&31)>>3), e=k&7; frag idx (mt*KCH+kc)*64+lane.
// Gate cols permuted n = 4j+q so the LSTM elementwise is block-local.
// Lesson log: R5 same-wave tail fusion serializes; R6 grid.sync ~40us/step;
// R7 zpackall grid 2048; R9 gzbig2 1/4-N coverage bug; R10/R12 tile AREA sets
// traffic (64x64/256blk sweet spot); R13 gzbig unroll4 neutral (FETCH 2x);
// R14 r concentrated on 32 CUs gates the step (-38%) -> spread as waves;
// R15 prologue fusion -50us; R16 nontemporal builtin needs int/float ptr.
// ---------------------------------------------------------------------------

using f32x4 = __attribute__((ext_vector_type(4))) float;
using f16x8 = __attribute__((ext_vector_type(8))) _Float16;
using fp16x2 = __attribute__((ext_vector_type(2))) __fp16;

union U4H8 { uint4 u; f16x8 h; fp16x2 p[4]; };
union GZU { uint2 u; __half2 h2[2]; };

__device__ __forceinline__ float sigm(float x){ return 1.0f/(1.0f + __expf(-x)); }
__device__ __forceinline__ float tanhfast(float x){
  x = fminf(fmaxf(x, -30.f), 30.f);
  float e = __expf(2.0f*x);
  return (e - 1.0f)/(e + 1.0f);
}

#define MFMA16(a,b,c) __builtin_amdgcn_mfma_f32_16x16x32_f16((a).h,(b).h,(c),0,0,0)

// --- launch 1: wft (bid<512) || bias2 (bid>=512) ----------------------------
__global__ void k_init(const float* __restrict__ wfeat, const float* __restrict__ wrnn,
                       const float* __restrict__ brnn, const float* __restrict__ bfeat,
                       float* __restrict__ wft, float* __restrict__ biasp){
  const int bid = blockIdx.x, tid = threadIdx.x;
  if (bid < 512){
    int idx = bid*256 + tid;                   // 131072
    int c = idx & 511; int j = idx >> 9;
    wft[c*256 + j] = wfeat[idx];
  } else {
    int wv = ((bid-512)*256 + tid) >> 6;       // 0..2047
    int lane = tid & 63;
    int g = (wv&3)*512 + (wv>>2);
    const float* wr = wrnn + (size_t)g*1280;
    float s = 0.f;
    for (int j = lane; j < 256; j += 64) s += bfeat[j]*wr[j];
    for (int off = 32; off; off >>= 1) s += __shfl_down(s, off, 64);
    if (lane == 0) biasp[wv] = brnn[g] + s;
  }
}

// --- launch 2: whp_part[s][kk][n] partial products (4 K-slices) -------------
__global__ void k_whp4(const float* __restrict__ wrnn, const float* __restrict__ wft,
                       float* __restrict__ whp_part){
  int s = blockIdx.x >> 8;
  int tl = blockIdx.x & 255;
  int bn = tl & 31, bk = tl >> 5;
  __shared__ float wrs[64][37];
  __shared__ float wfs[64][37];
  int tid = threadIdx.x;
  int tn = tid & 15, tk = tid >> 4;
  float accv[4][4];
  #pragma unroll
  for (int x=0;x<4;x++) for (int y=0;y<4;y++) accv[x][y]=0.f;
  for (int jc = s*64; jc < s*64+64; jc += 32){
    __syncthreads();
    for (int idx = tid; idx < 64*32; idx += 256){
      int r = idx >> 5, j = idx & 31;
      int n = bn*64 + r; int g = (n&3)*512 + (n>>2);
      wrs[r][j] = wrnn[(size_t)g*1280 + jc + j];
      wfs[r][j] = wft[(bk*64 + r)*256 + jc + j];
    }
    __syncthreads();
    for (int j=0;j<32;j++){
      float a[4], b[4];
      #pragma unroll
      for (int x=0;x<4;x++){ a[x] = wfs[tk*4+x][j]; b[x] = wrs[tn*4+x][j]; }
      #pragma unroll
      for (int x=0;x<4;x++)
        #pragma unroll
        for (int y=0;y<4;y++) accv[x][y] += a[x]*b[y];
    }
  }
  float* dst = whp_part + (size_t)s*1048576;
  for (int x=0;x<4;x++){
    int kk = bk*64 + tk*4 + x;
    for (int y=0;y<4;y++){
      int n = bn*64 + tn*4 + y;
      dst[(size_t)kk*2048 + n] = accv[x][y];
    }
  }
}

// --- launch 3: fused prep ----------------------------------------------------
// bid<512: rinit | [512,1536): packh0 | [1536,2560): bp_rec pack (inline whp
// sum) | [2560,3072): bpz pack | [3072,3136): bf pack | [3136,5184): zpackall
__global__ void k_prep(const float* __restrict__ z,
                       const float* __restrict__ r0, const float* __restrict__ h0,
                       const float* __restrict__ c0,
                       const float* __restrict__ wrnn, const float* __restrict__ wfeat,
                       const float* __restrict__ wft, const float* __restrict__ bfeat,
                       const float* __restrict__ whp_part,
                       float* __restrict__ rd32, __half* __restrict__ rd16,
                       __half* __restrict__ h16, float* __restrict__ c32,
                       __half* __restrict__ bp_rec, __half* __restrict__ bpz,
                       __half* __restrict__ bf_pack, __half* __restrict__ z16){
  __shared__ float hs[512];
  const int bid = blockIdx.x, tid = threadIdx.x;
  if (bid < 512){
    // rinit: rd0 = r0 - h0 @ Wf^T - b_feat
    const int row = bid, j = tid;
    for (int k = tid; k < 512; k += 256) hs[k] = h0[row*512 + k];
    __syncthreads();
    float acc = 0.f;
    for (int k=0;k<512;k++) acc += hs[k]*wft[k*256 + j];
    float rr = r0[row*256 + j] - acc - bfeat[j];
    rd32[row*256 + j] = rr;
    int ridx = (((row>>4)*8 + (j>>5))*64 + (row&15) + (((j&31)>>3)<<4))*8 + (j&7);
    rd16[ridx] = __float2half(rr);
  } else if (bid < 1536){
    // packh0: h0 -> frag, c0 -> c32
    int idx = (bid-512)*256 + tid;             // 262144
    int e = idx & 7, l = (idx>>3) & 63, kc = (idx>>9) & 15, mt = idx >> 13;
    int row = mt*16 + (l&15);
    int k = kc*32 + ((l>>4)<<3) + e;
    h16[idx] = __float2half(h0[row*512 + k]);
    c32[idx] = c0[idx];
  } else if (bid < 2560){
    // bp_rec pack, KCH=24, with inline 4-slice whp sum
    const int tot = 128*24*512;                // 1,572,864
    for (int idx = (bid-1536)*256 + tid; idx < tot; idx += 1024*256){
      int e = idx & 7; int l = (idx>>3) & 63;
      int kc = (idx>>9) % 24; int nt = (idx>>9) / 24;
      int k = kc*32 + ((l>>4)<<3) + e;
      int n = nt*16 + (l&15);
      int g = (n&3)*512 + (n>>2);
      float v;
      if (k < 256) v = wrnn[(size_t)g*1280 + k];
      else {
        size_t o = (size_t)(k-256)*2048 + n;
        v = whp_part[o] + whp_part[1048576+o] + whp_part[2097152+o]
            + whp_part[3145728+o] + wrnn[(size_t)g*1280 + k];
      }
      bp_rec[idx] = __float2half(v);
    }
  } else if (bid < 3072){
    // bpz pack, KCH=16 (Wz = wrnn cols 768..1279)
    const int tot = 128*16*512;                // 1,048,576
    for (int idx = (bid-2560)*256 + tid; idx < tot; idx += 512*256){
      int e = idx & 7; int l = (idx>>3) & 63;
      int kc = (idx>>9) & 15; int nt = (idx>>9) >> 4;
      int k = kc*32 + ((l>>4)<<3) + e;
      int n = nt*16 + (l&15);
      int g = (n&3)*512 + (n>>2);
      bpz[idx] = __float2half(wrnn[(size_t)g*1280 + 768 + k]);
    }
  } else if (bid < 3136){
    // bf pack, NT16=16, KCH=16 (Wf^T)
    const int tot = 16*16*512;                 // 131072
    for (int idx = (bid-3072)*256 + tid; idx < tot; idx += 64*256){
      int e = idx & 7; int l = (idx>>3) & 63;
      int kc = (idx>>9) & 15; int nt = (idx>>9) >> 4;
      int k = kc*32 + ((l>>4)<<3) + e;
      int n = nt*16 + (l&15);
      bf_pack[idx] = __float2half(wfeat[(size_t)n*512 + k]);
    }
  } else {
    // zpackall: one 4b x 8k block per thread (524288 items; R7 lesson)
    int u = (bid-3136)*256 + tid;
    int k0 = (u & 63) * 8;
    int b4 = (u >> 6) & 127;
    int t  = u >> 13;                          // 0..63
    int b = b4 * 4;
    int frag = (t*32 + (b>>4))*16 + (k0>>5);
    uint4 wv[4];
    #pragma unroll
    for (int j=0;j<4;j++){
      const float4* src = (const float4*)(z + ((size_t)((b+j)*64 + t))*512 + k0);
      float4 f0 = src[0], f1 = src[1];
      U4H8 a;
      a.p[0] = __builtin_amdgcn_cvt_pkrtz(f0.x, f0.y);
      a.p[1] = __builtin_amdgcn_cvt_pkrtz(f0.z, f0.w);
      a.p[2] = __builtin_amdgcn_cvt_pkrtz(f1.x, f1.y);
      a.p[3] = __builtin_amdgcn_cvt_pkrtz(f1.z, f1.w);
      wv[j] = a.u;
    }
    uint4* dst = (uint4*)z16 + (size_t)frag*64 + (b & 15) + (((k0 & 31) >> 3) << 4);
    #pragma unroll
    for (int j=0;j<4;j++) dst[j] = wv[j];
  }
}

// --- launch 4: big Gz GEMM: M=32768, N=2048, K=512 --------------------------
// 128x128 tiles; grid 4096 = [bmh:5][bn:4][xcd:3]; concurrent window L2-fits.
// gz stores NONTEMPORAL (ushort bit pattern): write stream bypasses L2.
__global__ __launch_bounds__(512) void k_gzbig(const __half* __restrict__ z16,
    const __half* __restrict__ bpz, const float* __restrict__ biasp,
    __half* __restrict__ gz){
  const int tid = threadIdx.x, lane = tid & 63, w = tid >> 6;
  const int wr = w >> 2, wc = w & 3;
  const int xcd = blockIdx.x & 7;
  const int bn  = (blockIdx.x >> 3) & 15;
  const int bmh = blockIdx.x >> 7;                       // 0..31
  const int bm  = xcd*32 + bmh;                          // 0..255
  const int tt = bm >> 2, bq = bm & 3;
  const int mt0 = tt*32 + bq*8 + wr*4;
  const int nt0 = bn*8 + wc*2;
  const uint4* A = (const uint4*)z16 + (size_t)(mt0*16)*64 + lane;
  const uint4* B = (const uint4*)bpz + (size_t)(nt0*16)*64 + lane;
  f32x4 acc[4][2];
  #pragma unroll
  for (int mi=0;mi<4;mi++){ acc[mi][0]=(f32x4){0,0,0,0}; acc[mi][1]=(f32x4){0,0,0,0}; }
  #pragma unroll 2
  for (int kc=0; kc<16; ++kc){
    U4H8 b0v, b1v;
    b0v.u = B[kc*64];
    b1v.u = B[(16+kc)*64];
    #pragma unroll
    for (int mi=0; mi<4; mi++){
      U4H8 a;
      a.u = A[(mi*16 + kc)*64];
      acc[mi][0] = MFMA16(a, b0v, acc[mi][0]);
      acc[mi][1] = MFMA16(a, b1v, acc[mi][1]);
    }
  }
  unsigned short* gzu = (unsigned short*)gz;
  #pragma unroll
  for (int ns=0; ns<2; ns++){
    int n = (nt0 + ns)*16 + (lane & 15);
    float bp = biasp[n];
    #pragma unroll
    for (int mi=0; mi<4; mi++){
      #pragma unroll
      for (int i=0; i<4; i++){
        int brow = bq*128 + wr*64 + mi*16 + ((lane>>4)<<2) + i;
        __builtin_nontemporal_store(
            __half_as_ushort(__float2half(acc[mi][ns][i] + bp)),
            &gzu[((size_t)(tt*512 + brow))*2048 + n]);
      }
    }
  }
}

// --- per-timestep kernel: 256 blocks x 640 thr (1 block/CU, 10 waves) -------
// waves 0-7: gate 64x64 K=768 (wave = 32x16 out, 6 indep 8-deep chains), gz/c32
// prefetched before the MFMA chains; waves 8-9: one 16x16 r-tile each
// (rb = bid*2 + w2; all 512 tiles), rd32 prefetched.
// mode 1 (final): r waves only -> out_r.
__global__ __launch_bounds__(640) void k_stepF(
    const __half* __restrict__ rd16_in, const __half* __restrict__ h16_in,
    float* __restrict__ rd32,
    __half* __restrict__ rd16_out, __half* __restrict__ h16_out,
    float* __restrict__ c32,
    const __half* __restrict__ gz,       // full gz; slice = step*1048576
    const __half* __restrict__ bp_rec, const __half* __restrict__ bf_pack,
    const float* __restrict__ bfeat,
    float* __restrict__ out_h, float* __restrict__ out_c, float* __restrict__ out_r,
    int step, int mode){
  __shared__ float cls[64][69];
  const int tid = threadIdx.x, lane = tid & 63;
  const int bid = blockIdx.x;
  // XCD-aware gate mapping: xcd (=bid&7) reuses 4 bn panels
  const int bm = (bid>>3) & 7;
  const int bn = (bid&7)*4 + (bid>>6);

  if (tid < 512){
    if (mode == 0){
      // ---- epilogue operand prefetch (hidden under the MFMA chains) ----
      const __half* gzt = gz + (size_t)step*1048576;
      const int jl0 = tid & 15,        row0 = tid >> 4;          // rep 0
      const int jl1 = (512+tid) & 15,  row1 = (512+tid) >> 4;    // rep 1
      const int gr0 = bm*64 + row0, j0 = bn*16 + jl0;
      const int gr1 = bm*64 + row1, j1 = bn*16 + jl1;
      GZU gu0, gu1;
      gu0.u = *(const uint2*)(gzt + (size_t)gr0*2048 + bn*64 + jl0*4);
      gu1.u = *(const uint2*)(gzt + (size_t)gr1*2048 + bn*64 + jl1*4);
      const float cold0 = c32[(size_t)gr0*512 + j0];
      const float cold1 = c32[(size_t)gr1*512 + j1];

      // ---- gate GEMM: wave = 32x16 out, 6 independent chains (8 deep) ----
      const int w = tid >> 6, wr = w >> 2, wc = w & 3;
      f32x4 a0A=(f32x4){0,0,0,0}, a0B=(f32x4){0,0,0,0}, a0C=(f32x4){0,0,0,0};
      f32x4 a1A=(f32x4){0,0,0,0}, a1B=(f32x4){0,0,0,0}, a1C=(f32x4){0,0,0,0};
      const int mtA = bm*4 + wr*2;
      const int nt  = bn*4 + wc;
      const uint4* a0p = (const uint4*)rd16_in + (size_t)(mtA*8)*64 + lane;
      const uint4* a1p = a0p + 8*64;
      const uint4* h0p = (const uint4*)h16_in + (size_t)(mtA*16)*64 + lane;
      const uint4* h1p = h0p + 16*64;
      const uint4* bp  = (const uint4*)bp_rec + (size_t)(nt*24)*64 + lane;
      #pragma unroll
      for (int kc=0; kc<8; ++kc){
        U4H8 a0,a1,b;
        a0.u = a0p[kc*64]; a1.u = a1p[kc*64]; b.u = bp[kc*64];
        a0A = MFMA16(a0,b,a0A);
        a1A = MFMA16(a1,b,a1A);
      }
      #pragma unroll
      for (int kc=0; kc<8; ++kc){
        U4H8 a0,a1,b;
        a0.u = h0p[kc*64]; a1.u = h1p[kc*64]; b.u = bp[(8+kc)*64];
        a0B = MFMA16(a0,b,a0B);
        a1B = MFMA16(a1,b,a1B);
      }
      #pragma unroll
      for (int kc=8; kc<16; ++kc){
        U4H8 a0,a1,b;
        a0.u = h0p[kc*64]; a1.u = h1p[kc*64]; b.u = bp[(8+kc)*64];
        a0C = MFMA16(a0,b,a0C);
        a1C = MFMA16(a1,b,a1C);
      }
      const f32x4 acc0 = (a0A + a0B) + a0C;
      const f32x4 acc1 = (a1A + a1B) + a1C;
      #pragma unroll
      for (int i=0; i<4; i++){
        cls[wr*32 +      ((lane>>4)<<2) + i][wc*16 + (lane&15)] = acc0[i];
        cls[wr*32 + 16 + ((lane>>4)<<2) + i][wc*16 + (lane&15)] = acc1[i];
      }
      __syncthreads();
      // ---- coalesced LSTM epilogue (prefetched gz/c32) ----
      #pragma unroll
      for (int rep=0; rep<2; rep++){
        const int row = rep ? row1 : row0;
        const int jl  = rep ? jl1  : jl0;
        const int grow = rep ? gr1 : gr0;
        const int j   = rep ? j1 : j0;
        const GZU gu  = rep ? gu1 : gu0;
        const float cold = rep ? cold1 : cold0;
        float g0 = cls[row][jl*4+0] + __half2float(gu.h2[0].x);
        float g1 = cls[row][jl*4+1] + __half2float(gu.h2[0].y);
        float g2 = cls[row][jl*4+2] + __half2float(gu.h2[1].x);
        float g3 = cls[row][jl*4+3] + __half2float(gu.h2[1].y);
        float f  = sigm(g0);
        float ii = sigm(g1);
        float s  = tanhfast(g2);
        float o  = sigm(g3);
        float cn = f*cold + ii*s;
        float hn = o*tanhfast(cn);
        c32[(size_t)grow*512 + j] = cn;
        int hidx = (((grow>>4)*16 + (j>>5))*64 + (grow&15) + (((j&31)>>3)<<4))*8 + (j&7);
        h16_out[hidx] = __float2half(hn);
        if (step == 63){
          out_h[(size_t)grow*512 + j] = hn;
          out_c[(size_t)grow*512 + j] = cn;
        }
      }
    }
  } else {
    // ---- TWO r waves: one 16x16 tile each, K=512 as 2x8 chains ----
    const int w2 = (tid - 512) >> 6;               // 0..1
    const int rb = bid*2 + w2;                     // 0..511
    const int mt = rb >> 4;                        // 0..31
    const int nc = rb & 15;                        // 0..15
    const int col = nc*16 + (lane&15);
    // prefetch rd32 (same-thread RMW; hidden under MFMA)
    float rdp[4];
    #pragma unroll
    for (int i=0;i<4;i++){
      const int grow = mt*16 + ((lane>>4)<<2) + i;
      rdp[i] = rd32[(size_t)grow*256 + col];
    }
    const float bfv = bfeat[col];
    const uint4* hp = (const uint4*)h16_in + (size_t)(mt*16)*64 + lane;
    const uint4* bf = (const uint4*)bf_pack + (size_t)(nc*16)*64 + lane;
    f32x4 r0v = (f32x4){0,0,0,0}, r1v = (f32x4){0,0,0,0};
    #pragma unroll 4
    for (int kc=0; kc<8; ++kc){
      U4H8 a,b;
      a.u = hp[kc*64]; b.u = bf[kc*64];
      r0v = MFMA16(a,b,r0v);
    }
    #pragma unroll 4
    for (int kc=8; kc<16; ++kc){
      U4H8 a,b;
      a.u = hp[kc*64]; b.u = bf[kc*64];
      r1v = MFMA16(a,b,r1v);
    }
    const f32x4 racc = r0v + r1v;
    #pragma unroll
    for (int i=0;i<4;i++){
      const int grow = mt*16 + ((lane>>4)<<2) + i;
      const size_t x = (size_t)grow*256 + col;
      const float rr = racc[i] + rdp[i] + bfv;
      if (mode == 1){
        out_r[x] = rr;
      } else {
        rd32[x] = rr;
        const int ridx = (((grow>>4)*8 + (col>>5))*64
                          + (grow&15) + (((col&31)>>3)<<4))*8 + (col&7);
        rd16_out[ridx] = __float2half(rr);
      }
    }
  }
}

// ---------------------------------------------------------------------------
extern "C" void kernel_launch(void* const* d_in, const int* in_sizes, int n_in,
                              void* d_out, int out_size, void* d_ws, size_t ws_size,
                              hipStream_t stream){
  const float* z     = (const float*)d_in[0];
  const float* r0    = (const float*)d_in[1];
  const float* h0    = (const float*)d_in[2];
  const float* c0    = (const float*)d_in[3];
  const float* wrnn  = (const float*)d_in[4];
  const float* brnn  = (const float*)d_in[5];
  const float* wfeat = (const float*)d_in[6];
  const float* bfeat = (const float*)d_in[7];
  float* out = (float*)d_out;

  char* wsb = (char*)d_ws;
  size_t off = 0;
  auto alloc = [&](size_t bytes)->char*{
    char* p = wsb + off; off = (off + bytes + 255) & ~(size_t)255; return p;
  };
  __half* z16     = (__half*)alloc((size_t)64*512*512*2);      // 33.5 MB
  __half* bp_rec  = (__half*)alloc((size_t)128*24*512*2);      // 3 MB
  __half* bpz     = (__half*)alloc((size_t)128*16*512*2);      // 2 MB
  __half* bf_pack = (__half*)alloc((size_t)16*16*512*2);
  float*  biasp   = (float*) alloc(2048*4);
  float*  wft32   = (float*) alloc((size_t)512*256*4);
  __half* h16A    = (__half*)alloc((size_t)512*512*2);
  __half* h16B    = (__half*)alloc((size_t)512*512*2);
  __half* rd16A   = (__half*)alloc((size_t)512*256*2);
  __half* rd16B   = (__half*)alloc((size_t)512*256*2);
  float*  rd32    = (float*) alloc((size_t)512*256*4);
  float*  c32     = (float*) alloc((size_t)512*512*4);
  __half* gz      = (__half*)alloc((size_t)64*512*2048*2);     // 128 MB
  (void)ws_size;
  // prologue-only alias inside gz region (dead before k_gzbig writes):
  float* whp_part = (float*)gz + 1048576;        // 16 MB @ gz+4MB

  k_init <<<dim3(1024), dim3(256), 0, stream>>>(wfeat, wrnn, brnn, bfeat, wft32, biasp);
  k_whp4 <<<dim3(1024), dim3(256), 0, stream>>>(wrnn, wft32, whp_part);
  k_prep <<<dim3(5184), dim3(256), 0, stream>>>(z, r0, h0, c0, wrnn, wfeat, wft32,
                                                bfeat, whp_part, rd32, rd16A, h16A,
                                                c32, bp_rec, bpz, bf_pack, z16);
  k_gzbig<<<dim3(4096), dim3(512), 0, stream>>>(z16, bpz, biasp, gz);

  __half* h16in = h16A;  __half* h16out = h16B;
  __half* rd16in = rd16A; __half* rd16out = rd16B;
  for (int t = 1; t <= 64; ++t){
    k_stepF<<<dim3(256), dim3(640), 0, stream>>>(
        rd16in, h16in, rd32, rd16out, h16out, c32, gz,
        bp_rec, bf_pack, bfeat,
        out + 131072, out + 393216, (float*)nullptr, t-1, 0);
    __half* th;
    th = h16in; h16in = h16out; h16out = th;
    th = rd16in; rd16in = rd16out; rd16out = th;
  }
  // final: r_64 = r_63 + h_64 @ Wf^T + b_feat -> d_out[0:131072)
  k_stepF<<<dim3(256), dim3(640), 0, stream>>>(
      rd16in, h16in, rd32, rd16out, h16out, c32, gz,
      bp_rec, bf_pack, bfeat,
      (float*)nullptr, (float*)nullptr, out, 64, 1);
}

// Round 18
// 763.284 us; speedup vs baseline: 1.0171x; 1.0171x over previous
//
#include <hip/hip_runtime.h>
#include <hip/hip_fp16.h>

// ---------------------------------------------------------------------------
// RecurrentRepresentationAggregator: 64-step LSTM-ish recurrence, B=512.
//   gates_t = [r_{t-1}, h_{t-1}, z_t] @ W_rnn^T + b_rnn      (N=2048, K=1280)
//   c_t = sig(f)*c + sig(i)*tanh(s);  h_t = sig(o)*tanh(c_t)
//   r_t = r_{t-1} + h_t @ W_feat^T + b_feat                   (N=256, K=512)
//
// Fold: gates_t = Gz_t + r_{t-2}·Wr + h_{t-1}·(Wh + Wf^T Wr).
// ALL Gz precomputed up front (zpack + k_gzbig, 128x128 tiles, 4096 blk,
// bid layout [bmh:5][bn:4][xcd:3] -> A+B L2-resident, FETCH 28 MB, plain
// stores so L2 merges the 2B gz writes into full lines).
// Prologue fused to 4 launches: k_init{wft,bias2} -> k_whp4 ->
// k_prep{rinit,packh0,pack_bprec(inline whp sum),pack_bpz,pack_bf,zpackall}
// -> k_gzbig.
// Per step ONE launch, grid 256 x 640 (1 block/CU, 10 waves):
//   waves 0-7: gate 64x64 tile, wave = 32x16 out, 2x12-deep chains wrapped in
//     s_setprio(1)/(0) (T5: role diversity vs r waves); cls-LDS + barrier +
//     coalesced epilogue (gz/c32 prefetched pre-MFMA).
//   waves 8-9: one 16x16 r-tile each (spread uniformly -- R14 lesson).
// h/rd carried in fp16 MFMA fragment layout; frag map (16x16x32):
// value(row,k) at lane=(row&15)+16*((k&31)>>3), e=k&7; frag idx (mt*KCH+kc)*64+lane.
// Gate cols permuted n = 4j+q so the LSTM elementwise is block-local.
// Lesson log: R5 same-wave tail fusion serializes; R6 grid.sync ~40us/step;
// R7 zpackall grid 2048; R9 gzbig2 1/4-N coverage bug; R10/R12 tile AREA sets
// traffic (64x64/256blk sweet spot); R13 gzbig unroll4 neutral (FETCH 2x);
// R14 r concentrated on 32 CUs gates the step (-38%); R15 prologue fusion
// -50us; R17 nontemporal 2B stores: WRITE 131->291 MB (no L2 merge) = net loss.
// ---------------------------------------------------------------------------

using f32x4 = __attribute__((ext_vector_type(4))) float;
using f16x8 = __attribute__((ext_vector_type(8))) _Float16;
using fp16x2 = __attribute__((ext_vector_type(2))) __fp16;

union U4H8 { uint4 u; f16x8 h; fp16x2 p[4]; };
union GZU { uint2 u; __half2 h2[2]; };

__device__ __forceinline__ float sigm(float x){ return 1.0f/(1.0f + __expf(-x)); }
__device__ __forceinline__ float tanhfast(float x){
  x = fminf(fmaxf(x, -30.f), 30.f);
  float e = __expf(2.0f*x);
  return (e - 1.0f)/(e + 1.0f);
}

#define MFMA16(a,b,c) __builtin_amdgcn_mfma_f32_16x16x32_f16((a).h,(b).h,(c),0,0,0)

// --- launch 1: wft (bid<512) || bias2 (bid>=512) ----------------------------
__global__ void k_init(const float* __restrict__ wfeat, const float* __restrict__ wrnn,
                       const float* __restrict__ brnn, const float* __restrict__ bfeat,
                       float* __restrict__ wft, float* __restrict__ biasp){
  const int bid = blockIdx.x, tid = threadIdx.x;
  if (bid < 512){
    int idx = bid*256 + tid;                   // 131072
    int c = idx & 511; int j = idx >> 9;
    wft[c*256 + j] = wfeat[idx];
  } else {
    int wv = ((bid-512)*256 + tid) >> 6;       // 0..2047
    int lane = tid & 63;
    int g = (wv&3)*512 + (wv>>2);
    const float* wr = wrnn + (size_t)g*1280;
    float s = 0.f;
    for (int j = lane; j < 256; j += 64) s += bfeat[j]*wr[j];
    for (int off = 32; off; off >>= 1) s += __shfl_down(s, off, 64);
    if (lane == 0) biasp[wv] = brnn[g] + s;
  }
}

// --- launch 2: whp_part[s][kk][n] partial products (4 K-slices) -------------
__global__ void k_whp4(const float* __restrict__ wrnn, const float* __restrict__ wft,
                       float* __restrict__ whp_part){
  int s = blockIdx.x >> 8;
  int tl = blockIdx.x & 255;
  int bn = tl & 31, bk = tl >> 5;
  __shared__ float wrs[64][37];
  __shared__ float wfs[64][37];
  int tid = threadIdx.x;
  int tn = tid & 15, tk = tid >> 4;
  float accv[4][4];
  #pragma unroll
  for (int x=0;x<4;x++) for (int y=0;y<4;y++) accv[x][y]=0.f;
  for (int jc = s*64; jc < s*64+64; jc += 32){
    __syncthreads();
    for (int idx = tid; idx < 64*32; idx += 256){
      int r = idx >> 5, j = idx & 31;
      int n = bn*64 + r; int g = (n&3)*512 + (n>>2);
      wrs[r][j] = wrnn[(size_t)g*1280 + jc + j];
      wfs[r][j] = wft[(bk*64 + r)*256 + jc + j];
    }
    __syncthreads();
    for (int j=0;j<32;j++){
      float a[4], b[4];
      #pragma unroll
      for (int x=0;x<4;x++){ a[x] = wfs[tk*4+x][j]; b[x] = wrs[tn*4+x][j]; }
      #pragma unroll
      for (int x=0;x<4;x++)
        #pragma unroll
        for (int y=0;y<4;y++) accv[x][y] += a[x]*b[y];
    }
  }
  float* dst = whp_part + (size_t)s*1048576;
  for (int x=0;x<4;x++){
    int kk = bk*64 + tk*4 + x;
    for (int y=0;y<4;y++){
      int n = bn*64 + tn*4 + y;
      dst[(size_t)kk*2048 + n] = accv[x][y];
    }
  }
}

// --- launch 3: fused prep ----------------------------------------------------
// bid<512: rinit | [512,1536): packh0 | [1536,2560): bp_rec pack (inline whp
// sum) | [2560,3072): bpz pack | [3072,3136): bf pack | [3136,5184): zpackall
__global__ void k_prep(const float* __restrict__ z,
                       const float* __restrict__ r0, const float* __restrict__ h0,
                       const float* __restrict__ c0,
                       const float* __restrict__ wrnn, const float* __restrict__ wfeat,
                       const float* __restrict__ wft, const float* __restrict__ bfeat,
                       const float* __restrict__ whp_part,
                       float* __restrict__ rd32, __half* __restrict__ rd16,
                       __half* __restrict__ h16, float* __restrict__ c32,
                       __half* __restrict__ bp_rec, __half* __restrict__ bpz,
                       __half* __restrict__ bf_pack, __half* __restrict__ z16){
  __shared__ float hs[512];
  const int bid = blockIdx.x, tid = threadIdx.x;
  if (bid < 512){
    // rinit: rd0 = r0 - h0 @ Wf^T - b_feat
    const int row = bid, j = tid;
    for (int k = tid; k < 512; k += 256) hs[k] = h0[row*512 + k];
    __syncthreads();
    float acc = 0.f;
    for (int k=0;k<512;k++) acc += hs[k]*wft[k*256 + j];
    float rr = r0[row*256 + j] - acc - bfeat[j];
    rd32[row*256 + j] = rr;
    int ridx = (((row>>4)*8 + (j>>5))*64 + (row&15) + (((j&31)>>3)<<4))*8 + (j&7);
    rd16[ridx] = __float2half(rr);
  } else if (bid < 1536){
    // packh0: h0 -> frag, c0 -> c32
    int idx = (bid-512)*256 + tid;             // 262144
    int e = idx & 7, l = (idx>>3) & 63, kc = (idx>>9) & 15, mt = idx >> 13;
    int row = mt*16 + (l&15);
    int k = kc*32 + ((l>>4)<<3) + e;
    h16[idx] = __float2half(h0[row*512 + k]);
    c32[idx] = c0[idx];
  } else if (bid < 2560){
    // bp_rec pack, KCH=24, with inline 4-slice whp sum
    const int tot = 128*24*512;                // 1,572,864
    for (int idx = (bid-1536)*256 + tid; idx < tot; idx += 1024*256){
      int e = idx & 7; int l = (idx>>3) & 63;
      int kc = (idx>>9) % 24; int nt = (idx>>9) / 24;
      int k = kc*32 + ((l>>4)<<3) + e;
      int n = nt*16 + (l&15);
      int g = (n&3)*512 + (n>>2);
      float v;
      if (k < 256) v = wrnn[(size_t)g*1280 + k];
      else {
        size_t o = (size_t)(k-256)*2048 + n;
        v = whp_part[o] + whp_part[1048576+o] + whp_part[2097152+o]
            + whp_part[3145728+o] + wrnn[(size_t)g*1280 + k];
      }
      bp_rec[idx] = __float2half(v);
    }
  } else if (bid < 3072){
    // bpz pack, KCH=16 (Wz = wrnn cols 768..1279)
    const int tot = 128*16*512;                // 1,048,576
    for (int idx = (bid-2560)*256 + tid; idx < tot; idx += 512*256){
      int e = idx & 7; int l = (idx>>3) & 63;
      int kc = (idx>>9) & 15; int nt = (idx>>9) >> 4;
      int k = kc*32 + ((l>>4)<<3) + e;
      int n = nt*16 + (l&15);
      int g = (n&3)*512 + (n>>2);
      bpz[idx] = __float2half(wrnn[(size_t)g*1280 + 768 + k]);
    }
  } else if (bid < 3136){
    // bf pack, NT16=16, KCH=16 (Wf^T)
    const int tot = 16*16*512;                 // 131072
    for (int idx = (bid-3072)*256 + tid; idx < tot; idx += 64*256){
      int e = idx & 7; int l = (idx>>3) & 63;
      int kc = (idx>>9) & 15; int nt = (idx>>9) >> 4;
      int k = kc*32 + ((l>>4)<<3) + e;
      int n = nt*16 + (l&15);
      bf_pack[idx] = __float2half(wfeat[(size_t)n*512 + k]);
    }
  } else {
    // zpackall: one 4b x 8k block per thread (524288 items; R7 lesson)
    int u = (bid-3136)*256 + tid;
    int k0 = (u & 63) * 8;
    int b4 = (u >> 6) & 127;
    int t  = u >> 13;                          // 0..63
    int b = b4 * 4;
    int frag = (t*32 + (b>>4))*16 + (k0>>5);
    uint4 wv[4];
    #pragma unroll
    for (int j=0;j<4;j++){
      const float4* src = (const float4*)(z + ((size_t)((b+j)*64 + t))*512 + k0);
      float4 f0 = src[0], f1 = src[1];
      U4H8 a;
      a.p[0] = __builtin_amdgcn_cvt_pkrtz(f0.x, f0.y);
      a.p[1] = __builtin_amdgcn_cvt_pkrtz(f0.z, f0.w);
      a.p[2] = __builtin_amdgcn_cvt_pkrtz(f1.x, f1.y);
      a.p[3] = __builtin_amdgcn_cvt_pkrtz(f1.z, f1.w);
      wv[j] = a.u;
    }
    uint4* dst = (uint4*)z16 + (size_t)frag*64 + (b & 15) + (((k0 & 31) >> 3) << 4);
    #pragma unroll
    for (int j=0;j<4;j++) dst[j] = wv[j];
  }
}

// --- launch 4: big Gz GEMM: M=32768, N=2048, K=512 --------------------------
// 128x128 tiles; grid 4096 = [bmh:5][bn:4][xcd:3]; concurrent window L2-fits.
__global__ __launch_bounds__(512) void k_gzbig(const __half* __restrict__ z16,
    const __half* __restrict__ bpz, const float* __restrict__ biasp,
    __half* __restrict__ gz){
  const int tid = threadIdx.x, lane = tid & 63, w = tid >> 6;
  const int wr = w >> 2, wc = w & 3;
  const int xcd = blockIdx.x & 7;
  const int bn  = (blockIdx.x >> 3) & 15;
  const int bmh = blockIdx.x >> 7;                       // 0..31
  const int bm  = xcd*32 + bmh;                          // 0..255
  const int tt = bm >> 2, bq = bm & 3;
  const int mt0 = tt*32 + bq*8 + wr*4;
  const int nt0 = bn*8 + wc*2;
  const uint4* A = (const uint4*)z16 + (size_t)(mt0*16)*64 + lane;
  const uint4* B = (const uint4*)bpz + (size_t)(nt0*16)*64 + lane;
  f32x4 acc[4][2];
  #pragma unroll
  for (int mi=0;mi<4;mi++){ acc[mi][0]=(f32x4){0,0,0,0}; acc[mi][1]=(f32x4){0,0,0,0}; }
  #pragma unroll 2
  for (int kc=0; kc<16; ++kc){
    U4H8 b0v, b1v;
    b0v.u = B[kc*64];
    b1v.u = B[(16+kc)*64];
    #pragma unroll
    for (int mi=0; mi<4; mi++){
      U4H8 a;
      a.u = A[(mi*16 + kc)*64];
      acc[mi][0] = MFMA16(a, b0v, acc[mi][0]);
      acc[mi][1] = MFMA16(a, b1v, acc[mi][1]);
    }
  }
  #pragma unroll
  for (int ns=0; ns<2; ns++){
    int n = (nt0 + ns)*16 + (lane & 15);
    float bp = biasp[n];
    #pragma unroll
    for (int mi=0; mi<4; mi++){
      #pragma unroll
      for (int i=0; i<4; i++){
        int brow = bq*128 + wr*64 + mi*16 + ((lane>>4)<<2) + i;
        gz[((size_t)(tt*512 + brow))*2048 + n] = __float2half(acc[mi][ns][i] + bp);
      }
    }
  }
}

// --- per-timestep kernel: 256 blocks x 640 thr (1 block/CU, 10 waves) -------
// waves 0-7: gate 64x64 K=768 (wave = 32x16 out, 2x12 chains, setprio-wrapped),
// gz/c32 prefetched before the MFMA chains; waves 8-9: one 16x16 r-tile each
// (rb = bid*2 + w2; all 512 tiles), rd32 prefetched.
// mode 1 (final): r waves only -> out_r.
__global__ __launch_bounds__(640) void k_stepF(
    const __half* __restrict__ rd16_in, const __half* __restrict__ h16_in,
    float* __restrict__ rd32,
    __half* __restrict__ rd16_out, __half* __restrict__ h16_out,
    float* __restrict__ c32,
    const __half* __restrict__ gz,       // full gz; slice = step*1048576
    const __half* __restrict__ bp_rec, const __half* __restrict__ bf_pack,
    const float* __restrict__ bfeat,
    float* __restrict__ out_h, float* __restrict__ out_c, float* __restrict__ out_r,
    int step, int mode){
  __shared__ float cls[64][69];
  const int tid = threadIdx.x, lane = tid & 63;
  const int bid = blockIdx.x;
  // XCD-aware gate mapping: xcd (=bid&7) reuses 4 bn panels
  const int bm = (bid>>3) & 7;
  const int bn = (bid&7)*4 + (bid>>6);

  if (tid < 512){
    if (mode == 0){
      // ---- epilogue operand prefetch (hidden under the MFMA chains) ----
      const __half* gzt = gz + (size_t)step*1048576;
      const int jl0 = tid & 15,        row0 = tid >> 4;          // rep 0
      const int jl1 = (512+tid) & 15,  row1 = (512+tid) >> 4;    // rep 1
      const int gr0 = bm*64 + row0, j0 = bn*16 + jl0;
      const int gr1 = bm*64 + row1, j1 = bn*16 + jl1;
      GZU gu0, gu1;
      gu0.u = *(const uint2*)(gzt + (size_t)gr0*2048 + bn*64 + jl0*4);
      gu1.u = *(const uint2*)(gzt + (size_t)gr1*2048 + bn*64 + jl1*4);
      const float cold0 = c32[(size_t)gr0*512 + j0];
      const float cold1 = c32[(size_t)gr1*512 + j1];

      // ---- gate GEMM: wave = 32x16 out, 4 independent chains (12 deep) ----
      const int w = tid >> 6, wr = w >> 2, wc = w & 3;
      f32x4 a0A=(f32x4){0,0,0,0}, a0B=(f32x4){0,0,0,0};
      f32x4 a1A=(f32x4){0,0,0,0}, a1B=(f32x4){0,0,0,0};
      const int mtA = bm*4 + wr*2;
      const int nt  = bn*4 + wc;
      const uint4* a0p = (const uint4*)rd16_in + (size_t)(mtA*8)*64 + lane;
      const uint4* a1p = a0p + 8*64;
      const uint4* h0p = (const uint4*)h16_in + (size_t)(mtA*16)*64 + lane;
      const uint4* h1p = h0p + 16*64;
      const uint4* bp  = (const uint4*)bp_rec + (size_t)(nt*24)*64 + lane;
      __builtin_amdgcn_s_setprio(1);
      #pragma unroll
      for (int kc=0; kc<4; ++kc){
        U4H8 a0,a1,b;
        a0.u = a0p[kc*64]; a1.u = a1p[kc*64]; b.u = bp[kc*64];
        a0A = MFMA16(a0,b,a0A);
        a1A = MFMA16(a1,b,a1A);
      }
      #pragma unroll
      for (int kc=4; kc<8; ++kc){
        U4H8 a0,a1,b;
        a0.u = a0p[kc*64]; a1.u = a1p[kc*64]; b.u = bp[kc*64];
        a0B = MFMA16(a0,b,a0B);
        a1B = MFMA16(a1,b,a1B);
      }
      #pragma unroll 4
      for (int kc=0; kc<8; ++kc){
        U4H8 a0,a1,b;
        a0.u = h0p[kc*64]; a1.u = h1p[kc*64]; b.u = bp[(8+kc)*64];
        a0A = MFMA16(a0,b,a0A);
        a1A = MFMA16(a1,b,a1A);
      }
      #pragma unroll 4
      for (int kc=8; kc<16; ++kc){
        U4H8 a0,a1,b;
        a0.u = h0p[kc*64]; a1.u = h1p[kc*64]; b.u = bp[(8+kc)*64];
        a0B = MFMA16(a0,b,a0B);
        a1B = MFMA16(a1,b,a1B);
      }
      __builtin_amdgcn_s_setprio(0);
      const f32x4 acc0 = a0A + a0B;
      const f32x4 acc1 = a1A + a1B;
      #pragma unroll
      for (int i=0; i<4; i++){
        cls[wr*32 +      ((lane>>4)<<2) + i][wc*16 + (lane&15)] = acc0[i];
        cls[wr*32 + 16 + ((lane>>4)<<2) + i][wc*16 + (lane&15)] = acc1[i];
      }
      __syncthreads();
      // ---- coalesced LSTM epilogue (prefetched gz/c32) ----
      #pragma unroll
      for (int rep=0; rep<2; rep++){
        const int row = rep ? row1 : row0;
        const int jl  = rep ? jl1  : jl0;
        const int grow = rep ? gr1 : gr0;
        const int j   = rep ? j1 : j0;
        const GZU gu  = rep ? gu1 : gu0;
        const float cold = rep ? cold1 : cold0;
        float g0 = cls[row][jl*4+0] + __half2float(gu.h2[0].x);
        float g1 = cls[row][jl*4+1] + __half2float(gu.h2[0].y);
        float g2 = cls[row][jl*4+2] + __half2float(gu.h2[1].x);
        float g3 = cls[row][jl*4+3] + __half2float(gu.h2[1].y);
        float f  = sigm(g0);
        float ii = sigm(g1);
        float s  = tanhfast(g2);
        float o  = sigm(g3);
        float cn = f*cold + ii*s;
        float hn = o*tanhfast(cn);
        c32[(size_t)grow*512 + j] = cn;
        int hidx = (((grow>>4)*16 + (j>>5))*64 + (grow&15) + (((j&31)>>3)<<4))*8 + (j&7);
        h16_out[hidx] = __float2half(hn);
        if (step == 63){
          out_h[(size_t)grow*512 + j] = hn;
          out_c[(size_t)grow*512 + j] = cn;
        }
      }
    }
  } else {
    // ---- TWO r waves: one 16x16 tile each, K=512 as 2x8 chains ----
    const int w2 = (tid - 512) >> 6;               // 0..1
    const int rb = bid*2 + w2;                     // 0..511
    const int mt = rb >> 4;                        // 0..31
    const int nc = rb & 15;                        // 0..15
    const int col = nc*16 + (lane&15);
    // prefetch rd32 (same-thread RMW; hidden under MFMA)
    float rdp[4];
    #pragma unroll
    for (int i=0;i<4;i++){
      const int grow = mt*16 + ((lane>>4)<<2) + i;
      rdp[i] = rd32[(size_t)grow*256 + col];
    }
    const float bfv = bfeat[col];
    const uint4* hp = (const uint4*)h16_in + (size_t)(mt*16)*64 + lane;
    const uint4* bf = (const uint4*)bf_pack + (size_t)(nc*16)*64 + lane;
    f32x4 r0v = (f32x4){0,0,0,0}, r1v = (f32x4){0,0,0,0};
    #pragma unroll 4
    for (int kc=0; kc<8; ++kc){
      U4H8 a,b;
      a.u = hp[kc*64]; b.u = bf[kc*64];
      r0v = MFMA16(a,b,r0v);
    }
    #pragma unroll 4
    for (int kc=8; kc<16; ++kc){
      U4H8 a,b;
      a.u = hp[kc*64]; b.u = bf[kc*64];
      r1v = MFMA16(a,b,r1v);
    }
    const f32x4 racc = r0v + r1v;
    #pragma unroll
    for (int i=0;i<4;i++){
      const int grow = mt*16 + ((lane>>4)<<2) + i;
      const size_t x = (size_t)grow*256 + col;
      const float rr = racc[i] + rdp[i] + bfv;
      if (mode == 1){
        out_r[x] = rr;
      } else {
        rd32[x] = rr;
        const int ridx = (((grow>>4)*8 + (col>>5))*64
                          + (grow&15) + (((col&31)>>3)<<4))*8 + (col&7);
        rd16_out[ridx] = __float2half(rr);
      }
    }
  }
}

// ---------------------------------------------------------------------------
extern "C" void kernel_launch(void* const* d_in, const int* in_sizes, int n_in,
                              void* d_out, int out_size, void* d_ws, size_t ws_size,
                              hipStream_t stream){
  const float* z     = (const float*)d_in[0];
  const float* r0    = (const float*)d_in[1];
  const float* h0    = (const float*)d_in[2];
  const float* c0    = (const float*)d_in[3];
  const float* wrnn  = (const float*)d_in[4];
  const float* brnn  = (const float*)d_in[5];
  const float* wfeat = (const float*)d_in[6];
  const float* bfeat = (const float*)d_in[7];
  float* out = (float*)d_out;

  char* wsb = (char*)d_ws;
  size_t off = 0;
  auto alloc = [&](size_t bytes)->char*{
    char* p = wsb + off; off = (off + bytes + 255) & ~(size_t)255; return p;
  };
  __half* z16     = (__half*)alloc((size_t)64*512*512*2);      // 33.5 MB
  __half* bp_rec  = (__half*)alloc((size_t)128*24*512*2);      // 3 MB
  __half* bpz     = (__half*)alloc((size_t)128*16*512*2);      // 2 MB
  __half* bf_pack = (__half*)alloc((size_t)16*16*512*2);
  float*  biasp   = (float*) alloc(2048*4);
  float*  wft32   = (float*) alloc((size_t)512*256*4);
  __half* h16A    = (__half*)alloc((size_t)512*512*2);
  __half* h16B    = (__half*)alloc((size_t)512*512*2);
  __half* rd16A   = (__half*)alloc((size_t)512*256*2);
  __half* rd16B   = (__half*)alloc((size_t)512*256*2);
  float*  rd32    = (float*) alloc((size_t)512*256*4);
  float*  c32     = (float*) alloc((size_t)512*512*4);
  __half* gz      = (__half*)alloc((size_t)64*512*2048*2);     // 128 MB
  (void)ws_size;
  // prologue-only alias inside gz region (dead before k_gzbig writes):
  float* whp_part = (float*)gz + 1048576;        // 16 MB @ gz+4MB

  k_init <<<dim3(1024), dim3(256), 0, stream>>>(wfeat, wrnn, brnn, bfeat, wft32, biasp);
  k_whp4 <<<dim3(1024), dim3(256), 0, stream>>>(wrnn, wft32, whp_part);
  k_prep <<<dim3(5184), dim3(256), 0, stream>>>(z, r0, h0, c0, wrnn, wfeat, wft32,
                                                bfeat, whp_part, rd32, rd16A, h16A,
                                                c32, bp_rec, bpz, bf_pack, z16);
  k_gzbig<<<dim3(4096), dim3(512), 0, stream>>>(z16, bpz, biasp, gz);

  __half* h16in = h16A;  __half* h16out = h16B;
  __half* rd16in = rd16A; __half* rd16out = rd16B;
  for (int t = 1; t <= 64; ++t){
    k_stepF<<<dim3(256), dim3(640), 0, stream>>>(
        rd16in, h16in, rd32, rd16out, h16out, c32, gz,
        bp_rec, bf_pack, bfeat,
        out + 131072, out + 393216, (float*)nullptr, t-1, 0);
    __half* th;
    th = h16in; h16in = h16out; h16out = th;
    th = rd16in; rd16in = rd16out; rd16out = th;
  }
  // final: r_64 = r_63 + h_64 @ Wf^T + b_feat -> d_out[0:131072)
  k_stepF<<<dim3(256), dim3(640), 0, stream>>>(
      rd16in, h16in, rd32, rd16out, h16out, c32, gz,
      bp_rec, bf_pack, bfeat,
      (float*)nullptr, (float*)nullptr, out, 64, 1);
}

// Round 19
// 749.534 us; speedup vs baseline: 1.0357x; 1.0183x over previous
//
#include <hip/hip_runtime.h>
#include <hip/hip_fp16.h>

// ---------------------------------------------------------------------------
// RecurrentRepresentationAggregator: 64-step LSTM-ish recurrence, B=512.
//   gates_t = [r_{t-1}, h_{t-1}, z_t] @ W_rnn^T + b_rnn      (N=2048, K=1280)
//   c_t = sig(f)*c + sig(i)*tanh(s);  h_t = sig(o)*tanh(c_t)
//   r_t = r_{t-1} + h_t @ W_feat^T + b_feat                   (N=256, K=512)
//
// Fold: gates_t = Gz_t + r_{t-2}·Wr + h_{t-1}·(Wh + Wf^T Wr).
// ALL Gz precomputed up front (zpack + k_gzbig, 128x128 tiles, 4096 blk,
// bid layout [bmh:5][bn:4][xcd:3] -> A+B L2-resident, FETCH 28 MB).
// Prologue fused to 4 launches: k_init{wft,bias2} -> k_whp4 ->
// k_prep{rinit,packh0,pack_bprec(inline whp sum),pack_bpz,pack_bf,zpackall}
// -> k_gzbig.
// Per step ONE launch, grid 256 x 640 (1 block/CU, 10 waves):
//   waves 0-7: gate 64x64 tile, wave = 32x16 out, 2x12-deep chains;
//     cls-LDS + barrier + coalesced epilogue (gz/c32 prefetched pre-MFMA).
//   waves 8-9: one 16x16 r-tile each (spread uniformly -- R14 lesson).
// h/rd carried in fp16 MFMA fragment layout; frag map (16x16x32):
// value(row,k) at lane=(row&15)+16*((k&31)>>3), e=k&7; frag idx (mt*KCH+kc)*64+lane.
// Gate cols permuted n = 4j+q so the LSTM elementwise is block-local.
// Lesson log: R5 same-wave tail fusion serializes; R6 grid.sync ~40us/step;
// R7 zpackall grid 2048; R9 gzbig2 1/4-N coverage bug; R10/R12 tile AREA sets
// traffic (64x64/256blk sweet spot); R13 gzbig unroll4 neutral (FETCH 2x);
// R14 r concentrated on 32 CUs gates the step (-38%); R15 prologue fusion
// -50us; R17 nontemporal 2B stores: WRITE 131->291 MB = net loss; R18 setprio
// null (barrier-lockstep gate waves). CONVERGED: steps are serial-launch-floor
// bound (~9us x 65); this is the measured-best (R15) configuration.
// ---------------------------------------------------------------------------

using f32x4 = __attribute__((ext_vector_type(4))) float;
using f16x8 = __attribute__((ext_vector_type(8))) _Float16;
using fp16x2 = __attribute__((ext_vector_type(2))) __fp16;

union U4H8 { uint4 u; f16x8 h; fp16x2 p[4]; };
union GZU { uint2 u; __half2 h2[2]; };

__device__ __forceinline__ float sigm(float x){ return 1.0f/(1.0f + __expf(-x)); }
__device__ __forceinline__ float tanhfast(float x){
  x = fminf(fmaxf(x, -30.f), 30.f);
  float e = __expf(2.0f*x);
  return (e - 1.0f)/(e + 1.0f);
}

#define MFMA16(a,b,c) __builtin_amdgcn_mfma_f32_16x16x32_f16((a).h,(b).h,(c),0,0,0)

// --- launch 1: wft (bid<512) || bias2 (bid>=512) ----------------------------
__global__ void k_init(const float* __restrict__ wfeat, const float* __restrict__ wrnn,
                       const float* __restrict__ brnn, const float* __restrict__ bfeat,
                       float* __restrict__ wft, float* __restrict__ biasp){
  const int bid = blockIdx.x, tid = threadIdx.x;
  if (bid < 512){
    int idx = bid*256 + tid;                   // 131072
    int c = idx & 511; int j = idx >> 9;
    wft[c*256 + j] = wfeat[idx];
  } else {
    int wv = ((bid-512)*256 + tid) >> 6;       // 0..2047
    int lane = tid & 63;
    int g = (wv&3)*512 + (wv>>2);
    const float* wr = wrnn + (size_t)g*1280;
    float s = 0.f;
    for (int j = lane; j < 256; j += 64) s += bfeat[j]*wr[j];
    for (int off = 32; off; off >>= 1) s += __shfl_down(s, off, 64);
    if (lane == 0) biasp[wv] = brnn[g] + s;
  }
}

// --- launch 2: whp_part[s][kk][n] partial products (4 K-slices) -------------
__global__ void k_whp4(const float* __restrict__ wrnn, const float* __restrict__ wft,
                       float* __restrict__ whp_part){
  int s = blockIdx.x >> 8;
  int tl = blockIdx.x & 255;
  int bn = tl & 31, bk = tl >> 5;
  __shared__ float wrs[64][37];
  __shared__ float wfs[64][37];
  int tid = threadIdx.x;
  int tn = tid & 15, tk = tid >> 4;
  float accv[4][4];
  #pragma unroll
  for (int x=0;x<4;x++) for (int y=0;y<4;y++) accv[x][y]=0.f;
  for (int jc = s*64; jc < s*64+64; jc += 32){
    __syncthreads();
    for (int idx = tid; idx < 64*32; idx += 256){
      int r = idx >> 5, j = idx & 31;
      int n = bn*64 + r; int g = (n&3)*512 + (n>>2);
      wrs[r][j] = wrnn[(size_t)g*1280 + jc + j];
      wfs[r][j] = wft[(bk*64 + r)*256 + jc + j];
    }
    __syncthreads();
    for (int j=0;j<32;j++){
      float a[4], b[4];
      #pragma unroll
      for (int x=0;x<4;x++){ a[x] = wfs[tk*4+x][j]; b[x] = wrs[tn*4+x][j]; }
      #pragma unroll
      for (int x=0;x<4;x++)
        #pragma unroll
        for (int y=0;y<4;y++) accv[x][y] += a[x]*b[y];
    }
  }
  float* dst = whp_part + (size_t)s*1048576;
  for (int x=0;x<4;x++){
    int kk = bk*64 + tk*4 + x;
    for (int y=0;y<4;y++){
      int n = bn*64 + tn*4 + y;
      dst[(size_t)kk*2048 + n] = accv[x][y];
    }
  }
}

// --- launch 3: fused prep ----------------------------------------------------
// bid<512: rinit | [512,1536): packh0 | [1536,2560): bp_rec pack (inline whp
// sum) | [2560,3072): bpz pack | [3072,3136): bf pack | [3136,5184): zpackall
__global__ void k_prep(const float* __restrict__ z,
                       const float* __restrict__ r0, const float* __restrict__ h0,
                       const float* __restrict__ c0,
                       const float* __restrict__ wrnn, const float* __restrict__ wfeat,
                       const float* __restrict__ wft, const float* __restrict__ bfeat,
                       const float* __restrict__ whp_part,
                       float* __restrict__ rd32, __half* __restrict__ rd16,
                       __half* __restrict__ h16, float* __restrict__ c32,
                       __half* __restrict__ bp_rec, __half* __restrict__ bpz,
                       __half* __restrict__ bf_pack, __half* __restrict__ z16){
  __shared__ float hs[512];
  const int bid = blockIdx.x, tid = threadIdx.x;
  if (bid < 512){
    // rinit: rd0 = r0 - h0 @ Wf^T - b_feat
    const int row = bid, j = tid;
    for (int k = tid; k < 512; k += 256) hs[k] = h0[row*512 + k];
    __syncthreads();
    float acc = 0.f;
    for (int k=0;k<512;k++) acc += hs[k]*wft[k*256 + j];
    float rr = r0[row*256 + j] - acc - bfeat[j];
    rd32[row*256 + j] = rr;
    int ridx = (((row>>4)*8 + (j>>5))*64 + (row&15) + (((j&31)>>3)<<4))*8 + (j&7);
    rd16[ridx] = __float2half(rr);
  } else if (bid < 1536){
    // packh0: h0 -> frag, c0 -> c32
    int idx = (bid-512)*256 + tid;             // 262144
    int e = idx & 7, l = (idx>>3) & 63, kc = (idx>>9) & 15, mt = idx >> 13;
    int row = mt*16 + (l&15);
    int k = kc*32 + ((l>>4)<<3) + e;
    h16[idx] = __float2half(h0[row*512 + k]);
    c32[idx] = c0[idx];
  } else if (bid < 2560){
    // bp_rec pack, KCH=24, with inline 4-slice whp sum
    const int tot = 128*24*512;                // 1,572,864
    for (int idx = (bid-1536)*256 + tid; idx < tot; idx += 1024*256){
      int e = idx & 7; int l = (idx>>3) & 63;
      int kc = (idx>>9) % 24; int nt = (idx>>9) / 24;
      int k = kc*32 + ((l>>4)<<3) + e;
      int n = nt*16 + (l&15);
      int g = (n&3)*512 + (n>>2);
      float v;
      if (k < 256) v = wrnn[(size_t)g*1280 + k];
      else {
        size_t o = (size_t)(k-256)*2048 + n;
        v = whp_part[o] + whp_part[1048576+o] + whp_part[2097152+o]
            + whp_part[3145728+o] + wrnn[(size_t)g*1280 + k];
      }
      bp_rec[idx] = __float2half(v);
    }
  } else if (bid < 3072){
    // bpz pack, KCH=16 (Wz = wrnn cols 768..1279)
    const int tot = 128*16*512;                // 1,048,576
    for (int idx = (bid-2560)*256 + tid; idx < tot; idx += 512*256){
      int e = idx & 7; int l = (idx>>3) & 63;
      int kc = (idx>>9) & 15; int nt = (idx>>9) >> 4;
      int k = kc*32 + ((l>>4)<<3) + e;
      int n = nt*16 + (l&15);
      int g = (n&3)*512 + (n>>2);
      bpz[idx] = __float2half(wrnn[(size_t)g*1280 + 768 + k]);
    }
  } else if (bid < 3136){
    // bf pack, NT16=16, KCH=16 (Wf^T)
    const int tot = 16*16*512;                 // 131072
    for (int idx = (bid-3072)*256 + tid; idx < tot; idx += 64*256){
      int e = idx & 7; int l = (idx>>3) & 63;
      int kc = (idx>>9) & 15; int nt = (idx>>9) >> 4;
      int k = kc*32 + ((l>>4)<<3) + e;
      int n = nt*16 + (l&15);
      bf_pack[idx] = __float2half(wfeat[(size_t)n*512 + k]);
    }
  } else {
    // zpackall: one 4b x 8k block per thread (524288 items; R7 lesson)
    int u = (bid-3136)*256 + tid;
    int k0 = (u & 63) * 8;
    int b4 = (u >> 6) & 127;
    int t  = u >> 13;                          // 0..63
    int b = b4 * 4;
    int frag = (t*32 + (b>>4))*16 + (k0>>5);
    uint4 wv[4];
    #pragma unroll
    for (int j=0;j<4;j++){
      const float4* src = (const float4*)(z + ((size_t)((b+j)*64 + t))*512 + k0);
      float4 f0 = src[0], f1 = src[1];
      U4H8 a;
      a.p[0] = __builtin_amdgcn_cvt_pkrtz(f0.x, f0.y);
      a.p[1] = __builtin_amdgcn_cvt_pkrtz(f0.z, f0.w);
      a.p[2] = __builtin_amdgcn_cvt_pkrtz(f1.x, f1.y);
      a.p[3] = __builtin_amdgcn_cvt_pkrtz(f1.z, f1.w);
      wv[j] = a.u;
    }
    uint4* dst = (uint4*)z16 + (size_t)frag*64 + (b & 15) + (((k0 & 31) >> 3) << 4);
    #pragma unroll
    for (int j=0;j<4;j++) dst[j] = wv[j];
  }
}

// --- launch 4: big Gz GEMM: M=32768, N=2048, K=512 --------------------------
// 128x128 tiles; grid 4096 = [bmh:5][bn:4][xcd:3]; concurrent window L2-fits.
__global__ __launch_bounds__(512) void k_gzbig(const __half* __restrict__ z16,
    const __half* __restrict__ bpz, const float* __restrict__ biasp,
    __half* __restrict__ gz){
  const int tid = threadIdx.x, lane = tid & 63, w = tid >> 6;
  const int wr = w >> 2, wc = w & 3;
  const int xcd = blockIdx.x & 7;
  const int bn  = (blockIdx.x >> 3) & 15;
  const int bmh = blockIdx.x >> 7;                       // 0..31
  const int bm  = xcd*32 + bmh;                          // 0..255
  const int tt = bm >> 2, bq = bm & 3;
  const int mt0 = tt*32 + bq*8 + wr*4;
  const int nt0 = bn*8 + wc*2;
  const uint4* A = (const uint4*)z16 + (size_t)(mt0*16)*64 + lane;
  const uint4* B = (const uint4*)bpz + (size_t)(nt0*16)*64 + lane;
  f32x4 acc[4][2];
  #pragma unroll
  for (int mi=0;mi<4;mi++){ acc[mi][0]=(f32x4){0,0,0,0}; acc[mi][1]=(f32x4){0,0,0,0}; }
  #pragma unroll 2
  for (int kc=0; kc<16; ++kc){
    U4H8 b0v, b1v;
    b0v.u = B[kc*64];
    b1v.u = B[(16+kc)*64];
    #pragma unroll
    for (int mi=0; mi<4; mi++){
      U4H8 a;
      a.u = A[(mi*16 + kc)*64];
      acc[mi][0] = MFMA16(a, b0v, acc[mi][0]);
      acc[mi][1] = MFMA16(a, b1v, acc[mi][1]);
    }
  }
  #pragma unroll
  for (int ns=0; ns<2; ns++){
    int n = (nt0 + ns)*16 + (lane & 15);
    float bp = biasp[n];
    #pragma unroll
    for (int mi=0; mi<4; mi++){
      #pragma unroll
      for (int i=0; i<4; i++){
        int brow = bq*128 + wr*64 + mi*16 + ((lane>>4)<<2) + i;
        gz[((size_t)(tt*512 + brow))*2048 + n] = __float2half(acc[mi][ns][i] + bp);
      }
    }
  }
}

// --- per-timestep kernel: 256 blocks x 640 thr (1 block/CU, 10 waves) -------
// waves 0-7: gate 64x64 K=768 (wave = 32x16 out, 2x12 chains), gz/c32
// prefetched before the MFMA chains; waves 8-9: one 16x16 r-tile each
// (rb = bid*2 + w2; all 512 tiles), rd32 prefetched.
// mode 1 (final): r waves only -> out_r.
__global__ __launch_bounds__(640) void k_stepF(
    const __half* __restrict__ rd16_in, const __half* __restrict__ h16_in,
    float* __restrict__ rd32,
    __half* __restrict__ rd16_out, __half* __restrict__ h16_out,
    float* __restrict__ c32,
    const __half* __restrict__ gz,       // full gz; slice = step*1048576
    const __half* __restrict__ bp_rec, const __half* __restrict__ bf_pack,
    const float* __restrict__ bfeat,
    float* __restrict__ out_h, float* __restrict__ out_c, float* __restrict__ out_r,
    int step, int mode){
  __shared__ float cls[64][69];
  const int tid = threadIdx.x, lane = tid & 63;
  const int bid = blockIdx.x;
  // XCD-aware gate mapping: xcd (=bid&7) reuses 4 bn panels
  const int bm = (bid>>3) & 7;
  const int bn = (bid&7)*4 + (bid>>6);

  if (tid < 512){
    if (mode == 0){
      // ---- epilogue operand prefetch (hidden under the MFMA chains) ----
      const __half* gzt = gz + (size_t)step*1048576;
      const int jl0 = tid & 15,        row0 = tid >> 4;          // rep 0
      const int jl1 = (512+tid) & 15,  row1 = (512+tid) >> 4;    // rep 1
      const int gr0 = bm*64 + row0, j0 = bn*16 + jl0;
      const int gr1 = bm*64 + row1, j1 = bn*16 + jl1;
      GZU gu0, gu1;
      gu0.u = *(const uint2*)(gzt + (size_t)gr0*2048 + bn*64 + jl0*4);
      gu1.u = *(const uint2*)(gzt + (size_t)gr1*2048 + bn*64 + jl1*4);
      const float cold0 = c32[(size_t)gr0*512 + j0];
      const float cold1 = c32[(size_t)gr1*512 + j1];

      // ---- gate GEMM: wave = 32x16 out, 4 independent chains (12 deep) ----
      const int w = tid >> 6, wr = w >> 2, wc = w & 3;
      f32x4 a0A=(f32x4){0,0,0,0}, a0B=(f32x4){0,0,0,0};
      f32x4 a1A=(f32x4){0,0,0,0}, a1B=(f32x4){0,0,0,0};
      const int mtA = bm*4 + wr*2;
      const int nt  = bn*4 + wc;
      const uint4* a0p = (const uint4*)rd16_in + (size_t)(mtA*8)*64 + lane;
      const uint4* a1p = a0p + 8*64;
      const uint4* h0p = (const uint4*)h16_in + (size_t)(mtA*16)*64 + lane;
      const uint4* h1p = h0p + 16*64;
      const uint4* bp  = (const uint4*)bp_rec + (size_t)(nt*24)*64 + lane;
      #pragma unroll
      for (int kc=0; kc<4; ++kc){
        U4H8 a0,a1,b;
        a0.u = a0p[kc*64]; a1.u = a1p[kc*64]; b.u = bp[kc*64];
        a0A = MFMA16(a0,b,a0A);
        a1A = MFMA16(a1,b,a1A);
      }
      #pragma unroll
      for (int kc=4; kc<8; ++kc){
        U4H8 a0,a1,b;
        a0.u = a0p[kc*64]; a1.u = a1p[kc*64]; b.u = bp[kc*64];
        a0B = MFMA16(a0,b,a0B);
        a1B = MFMA16(a1,b,a1B);
      }
      #pragma unroll 4
      for (int kc=0; kc<8; ++kc){
        U4H8 a0,a1,b;
        a0.u = h0p[kc*64]; a1.u = h1p[kc*64]; b.u = bp[(8+kc)*64];
        a0A = MFMA16(a0,b,a0A);
        a1A = MFMA16(a1,b,a1A);
      }
      #pragma unroll 4
      for (int kc=8; kc<16; ++kc){
        U4H8 a0,a1,b;
        a0.u = h0p[kc*64]; a1.u = h1p[kc*64]; b.u = bp[(8+kc)*64];
        a0B = MFMA16(a0,b,a0B);
        a1B = MFMA16(a1,b,a1B);
      }
      const f32x4 acc0 = a0A + a0B;
      const f32x4 acc1 = a1A + a1B;
      #pragma unroll
      for (int i=0; i<4; i++){
        cls[wr*32 +      ((lane>>4)<<2) + i][wc*16 + (lane&15)] = acc0[i];
        cls[wr*32 + 16 + ((lane>>4)<<2) + i][wc*16 + (lane&15)] = acc1[i];
      }
      __syncthreads();
      // ---- coalesced LSTM epilogue (prefetched gz/c32) ----
      #pragma unroll
      for (int rep=0; rep<2; rep++){
        const int row = rep ? row1 : row0;
        const int jl  = rep ? jl1  : jl0;
        const int grow = rep ? gr1 : gr0;
        const int j   = rep ? j1 : j0;
        const GZU gu  = rep ? gu1 : gu0;
        const float cold = rep ? cold1 : cold0;
        float g0 = cls[row][jl*4+0] + __half2float(gu.h2[0].x);
        float g1 = cls[row][jl*4+1] + __half2float(gu.h2[0].y);
        float g2 = cls[row][jl*4+2] + __half2float(gu.h2[1].x);
        float g3 = cls[row][jl*4+3] + __half2float(gu.h2[1].y);
        float f  = sigm(g0);
        float ii = sigm(g1);
        float s  = tanhfast(g2);
        float o  = sigm(g3);
        float cn = f*cold + ii*s;
        float hn = o*tanhfast(cn);
        c32[(size_t)grow*512 + j] = cn;
        int hidx = (((grow>>4)*16 + (j>>5))*64 + (grow&15) + (((j&31)>>3)<<4))*8 + (j&7);
        h16_out[hidx] = __float2half(hn);
        if (step == 63){
          out_h[(size_t)grow*512 + j] = hn;
          out_c[(size_t)grow*512 + j] = cn;
        }
      }
    }
  } else {
    // ---- TWO r waves: one 16x16 tile each, K=512 as 2x8 chains ----
    const int w2 = (tid - 512) >> 6;               // 0..1
    const int rb = bid*2 + w2;                     // 0..511
    const int mt = rb >> 4;                        // 0..31
    const int nc = rb & 15;                        // 0..15
    const int col = nc*16 + (lane&15);
    // prefetch rd32 (same-thread RMW; hidden under MFMA)
    float rdp[4];
    #pragma unroll
    for (int i=0;i<4;i++){
      const int grow = mt*16 + ((lane>>4)<<2) + i;
      rdp[i] = rd32[(size_t)grow*256 + col];
    }
    const float bfv = bfeat[col];
    const uint4* hp = (const uint4*)h16_in + (size_t)(mt*16)*64 + lane;
    const uint4* bf = (const uint4*)bf_pack + (size_t)(nc*16)*64 + lane;
    f32x4 r0v = (f32x4){0,0,0,0}, r1v = (f32x4){0,0,0,0};
    #pragma unroll 4
    for (int kc=0; kc<8; ++kc){
      U4H8 a,b;
      a.u = hp[kc*64]; b.u = bf[kc*64];
      r0v = MFMA16(a,b,r0v);
    }
    #pragma unroll 4
    for (int kc=8; kc<16; ++kc){
      U4H8 a,b;
      a.u = hp[kc*64]; b.u = bf[kc*64];
      r1v = MFMA16(a,b,r1v);
    }
    const f32x4 racc = r0v + r1v;
    #pragma unroll
    for (int i=0;i<4;i++){
      const int grow = mt*16 + ((lane>>4)<<2) + i;
      const size_t x = (size_t)grow*256 + col;
      const float rr = racc[i] + rdp[i] + bfv;
      if (mode == 1){
        out_r[x] = rr;
      } else {
        rd32[x] = rr;
        const int ridx = (((grow>>4)*8 + (col>>5))*64
                          + (grow&15) + (((col&31)>>3)<<4))*8 + (col&7);
        rd16_out[ridx] = __float2half(rr);
      }
    }
  }
}

// ---------------------------------------------------------------------------
extern "C" void kernel_launch(void* const* d_in, const int* in_sizes, int n_in,
                              void* d_out, int out_size, void* d_ws, size_t ws_size,
                              hipStream_t stream){
  const float* z     = (const float*)d_in[0];
  const float* r0    = (const float*)d_in[1];
  const float* h0    = (const float*)d_in[2];
  const float* c0    = (const float*)d_in[3];
  const float* wrnn  = (const float*)d_in[4];
  const float* brnn  = (const float*)d_in[5];
  const float* wfeat = (const float*)d_in[6];
  const float* bfeat = (const float*)d_in[7];
  float* out = (float*)d_out;

  char* wsb = (char*)d_ws;
  size_t off = 0;
  auto alloc = [&](size_t bytes)->char*{
    char* p = wsb + off; off = (off + bytes + 255) & ~(size_t)255; return p;
  };
  __half* z16     = (__half*)alloc((size_t)64*512*512*2);      // 33.5 MB
  __half* bp_rec  = (__half*)alloc((size_t)128*24*512*2);      // 3 MB
  __half* bpz     = (__half*)alloc((size_t)128*16*512*2);      // 2 MB
  __half* bf_pack = (__half*)alloc((size_t)16*16*512*2);
  float*  biasp   = (float*) alloc(2048*4);
  float*  wft32   = (float*) alloc((size_t)512*256*4);
  __half* h16A    = (__half*)alloc((size_t)512*512*2);
  __half* h16B    = (__half*)alloc((size_t)512*512*2);
  __half* rd16A   = (__half*)alloc((size_t)512*256*2);
  __half* rd16B   = (__half*)alloc((size_t)512*256*2);
  float*  rd32    = (float*) alloc((size_t)512*256*4);
  float*  c32     = (float*) alloc((size_t)512*512*4);
  __half* gz      = (__half*)alloc((size_t)64*512*2048*2);     // 128 MB
  (void)ws_size;
  // prologue-only alias inside gz region (dead before k_gzbig writes):
  float* whp_part = (float*)gz + 1048576;        // 16 MB @ gz+4MB

  k_init <<<dim3(1024), dim3(256), 0, stream>>>(wfeat, wrnn, brnn, bfeat, wft32, biasp);
  k_whp4 <<<dim3(1024), dim3(256), 0, stream>>>(wrnn, wft32, whp_part);
  k_prep <<<dim3(5184), dim3(256), 0, stream>>>(z, r0, h0, c0, wrnn, wfeat, wft32,
                                                bfeat, whp_part, rd32, rd16A, h16A,
                                                c32, bp_rec, bpz, bf_pack, z16);
  k_gzbig<<<dim3(4096), dim3(512), 0, stream>>>(z16, bpz, biasp, gz);

  __half* h16in = h16A;  __half* h16out = h16B;
  __half* rd16in = rd16A; __half* rd16out = rd16B;
  for (int t = 1; t <= 64; ++t){
    k_stepF<<<dim3(256), dim3(640), 0, stream>>>(
        rd16in, h16in, rd32, rd16out, h16out, c32, gz,
        bp_rec, bf_pack, bfeat,
        out + 131072, out + 393216, (float*)nullptr, t-1, 0);
    __half* th;
    th = h16in; h16in = h16out; h16out = th;
    th = rd16in; rd16in = rd16out; rd16out = th;
  }
  // final: r_64 = r_63 + h_64 @ Wf^T + b_feat -> d_out[0:131072)
  k_stepF<<<dim3(256), dim3(640), 0, stream>>>(
      rd16in, h16in, rd32, rd16out, h16out, c32, gz,
      bp_rec, bf_pack, bfeat,
      (float*)nullptr, (float*)nullptr, out, 64, 1);
}